// Round 13
// baseline (104.369 us; speedup 1.0000x reference)
//
#include <hip/hip_runtime.h>
#include <hip/hip_bf16.h>
#include <cstdint>

#define RST 16777216  // 4096*4096 floats per rating class
typedef unsigned short u16;
typedef unsigned char u8;
typedef unsigned int u32;
typedef __attribute__((ext_vector_type(8))) short short8v;   // 8 bf16 in 4 VGPRs
typedef __attribute__((ext_vector_type(4))) float f32x4;

__device__ __forceinline__ u16 f2bf(float x){
  unsigned int b = __float_as_uint(x);
  unsigned int r = (b + 0x7FFFu + ((b >> 16) & 1u)) >> 16;
  return (u16)r;
}
__device__ __forceinline__ float bf2f(u16 h){
  return __uint_as_float(((unsigned int)h) << 16);
}
__device__ __forceinline__ void split8(const float* fa, short8v& hi, short8v& lo){
#pragma unroll
  for (int e = 0; e < 8; e++){
    u16 h = f2bf(fa[e]);
    hi[e] = (short)h;
    lo[e] = (short)f2bf(fa[e] - bf2f(h));
  }
}
__device__ __forceinline__ int cnt_not5(u32 w){
  int c = 0;
  c += ((w & 255u) != 5u); c += (((w >> 8) & 255u) != 5u);
  c += (((w >> 16) & 255u) != 5u); c += ((w >> 24) != 5u);
  return c;
}

// ---------------------------------------------------------------------------
// K1: label extraction + di row-counts. One block per batch-row i. (r3 form)
// ---------------------------------------------------------------------------
__global__ __launch_bounds__(256) void k_labels(const int* __restrict__ u, const int* __restrict__ v,
                                                const float* __restrict__ ratings, u8* __restrict__ L,
                                                int* __restrict__ di){
  __shared__ float row[4096];
  __shared__ int wsum[4];
  int i = blockIdx.x;
  int tid = threadIdx.x;
  int lane = tid & 63, wid = tid >> 6;
  int U = u[i];
  int j0 = tid * 8;
  int vj[8];
#pragma unroll
  for (int k = 0; k < 8; k++) vj[k] = v[j0 + k];
  int lab[8];
#pragma unroll
  for (int k = 0; k < 8; k++) lab[k] = 5;
  const float* rbase = ratings + (size_t)U * 4096;
  for (int c = 0; c < 5; c++){
    const float4* src = (const float4*)(rbase + (size_t)c * RST);
#pragma unroll
    for (int k = 0; k < 4; k++) ((float4*)row)[tid + k*256] = src[tid + k*256];
    __syncthreads();
#pragma unroll
    for (int k = 0; k < 8; k++) if (row[vj[k]] > 0.5f) lab[k] = c;
    __syncthreads();
  }
  unsigned int lo = 0, hi = 0;
  int cnt = 0;
#pragma unroll
  for (int k = 0; k < 4; k++){
    lo |= ((unsigned)lab[k]) << (8*k); hi |= ((unsigned)lab[k+4]) << (8*k);
    cnt += (lab[k] != 5); cnt += (lab[k+4] != 5);
  }
  *(uint2*)(L + (size_t)i * 2048 + j0) = make_uint2(lo, hi);
#pragma unroll
  for (int o = 32; o > 0; o >>= 1) cnt += __shfl_down(cnt, o);
  if (lane == 0) wsum[wid] = cnt;
  __syncthreads();
  if (tid == 0) di[i] = wsum[0] + wsum[1] + wsum[2] + wsum[3];
}

// ---------------------------------------------------------------------------
// K2: fused [byte transpose L->LT] + [support via split-bf16 MFMA].
// Support output now stored PACKED-TRANSPOSED: SP[c][h][n] = (bf16hi<<16)|bf16lo
// so k_agg B-frags are contiguous 32B loads.
// ---------------------------------------------------------------------------
__global__ __launch_bounds__(256) void k_trsup(const u8* __restrict__ L, u8* __restrict__ LT,
    const int* __restrict__ u, const int* __restrict__ v,
    const float* __restrict__ u_emb, const float* __restrict__ v_emb, const float* __restrict__ gc_w,
    u32* __restrict__ SP){
  __shared__ u8 tile[64][64];
  int tid = threadIdx.x;
  if (blockIdx.x < 1024){
    int jb = blockIdx.x & 31, ib = blockIdx.x >> 5;
    int i0 = ib * 64, j0 = jb * 64;
    int r = tid >> 2, cq = tid & 3;
    uint4 d = *(const uint4*)(L + (size_t)(i0 + r) * 2048 + j0 + cq * 16);
    *(uint4*)&tile[r][cq * 16] = d;
    __syncthreads();
    u8 ob[16];
#pragma unroll
    for (int k = 0; k < 16; k++) ob[k] = tile[cq * 16 + k][r];
    *(uint4*)(LT + (size_t)(j0 + r) * 2048 + i0 + cq * 16) = *(uint4*)ob;
  } else {
    int b = blockIdx.x - 1024;
    int c = b >> 6, nblk = b & 63;
    int lane = tid & 63, wv = tid >> 6;
    int m = lane & 15, q = lane >> 4;
    int n0 = nblk * 64;
    bool uside = (n0 < 2048);
    const int* nidx = uside ? u : v;
    const float* emb = uside ? u_emb : v_emb;
    int nbase = uside ? n0 : (n0 - 2048);
    int h0 = wv * 16;
    short8v bh[2], bl[2];
#pragma unroll
    for (int ch = 0; ch < 2; ch++){
      const float* wp = gc_w + c * 4096 + (ch * 32 + q * 8) * 64 + h0 + m;
      float fb[8];
#pragma unroll
      for (int e = 0; e < 8; e++) fb[e] = wp[e * 64];
      split8(fb, bh[ch], bl[ch]);
    }
#pragma unroll
    for (int rt = 0; rt < 4; rt++){
      const float* xr = emb + (size_t)nidx[nbase + rt * 16 + m] * 64;
      f32x4 acc = {0.f, 0.f, 0.f, 0.f};
#pragma unroll
      for (int ch = 0; ch < 2; ch++){
        float fa[8];
        *(float4*)&fa[0] = *(const float4*)(xr + ch * 32 + q * 8);
        *(float4*)&fa[4] = *(const float4*)(xr + ch * 32 + q * 8 + 4);
        short8v ah, al;
        split8(fa, ah, al);
        acc = __builtin_amdgcn_mfma_f32_16x16x32_bf16(ah, bh[ch], acc, 0, 0, 0);
        acc = __builtin_amdgcn_mfma_f32_16x16x32_bf16(ah, bl[ch], acc, 0, 0, 0);
        acc = __builtin_amdgcn_mfma_f32_16x16x32_bf16(al, bh[ch], acc, 0, 0, 0);
      }
      int h = h0 + m;
      int rbase = n0 + rt * 16 + q * 4;
#pragma unroll
      for (int reg = 0; reg < 4; reg++){
        float val = acc[reg];
        u16 vh = f2bf(val);
        u16 vl = f2bf(val - bf2f(vh));
        SP[(((size_t)c * 64 + h) << 12) + rbase + reg] = (((u32)vh) << 16) | (u32)vl;
      }
    }
  }
}

// ---------------------------------------------------------------------------
// K3: DENSE masked-MFMA aggregate. agg[r,h] = sum_c sum_j (row[r][j]==c)*S[c,j,h].
// Grid (16 k-chunks x 64 row-blocks); block = 4 waves, each owns one h-tile.
// A-frags built from L/LT bytes (exact bf16 0/1 masks); B-frags = SP packed
// split-bf16, contiguous loads. 2 MFMAs per class (mask exact => no lo*hi).
// Partials to aggp[kc][r][h]; reduced in k_hidden.
// ---------------------------------------------------------------------------
__global__ __launch_bounds__(256) void k_agg(const u8* __restrict__ L, const u8* __restrict__ LT,
    const u32* __restrict__ SP, float* __restrict__ aggp){
  int tid = threadIdx.x;
  int lane = tid & 63, wv = tid >> 6;
  int m = lane & 15, q = lane >> 4;
  int kc = blockIdx.x;        // 0..15
  int rb = blockIdx.y;        // 0..63
  int r0 = rb * 64;
  bool uside = (r0 < 2048);
  const u8* Ab = uside ? (L + (size_t)r0 * 2048) : (LT + (size_t)(r0 - 2048) * 2048);
  int nb = uside ? 2048 : 0;
  int h0 = wv * 16;
  f32x4 acc[4];
#pragma unroll
  for (int it = 0; it < 4; it++) acc[it] = (f32x4){0.f, 0.f, 0.f, 0.f};
  for (int ks = 0; ks < 4; ks++){
    int j0 = (kc * 4 + ks) * 32;
    short8v bh[5], bl[5];
#pragma unroll
    for (int c = 0; c < 5; c++){
      const uint4* bp = (const uint4*)(SP + (((size_t)c * 64 + h0 + m) << 12) + nb + j0 + q * 8);
      uint4 wA = bp[0], wB = bp[1];
      u32 wws[8] = {wA.x, wA.y, wA.z, wA.w, wB.x, wB.y, wB.z, wB.w};
#pragma unroll
      for (int e = 0; e < 8; e++){
        bh[c][e] = (short)(wws[e] >> 16);
        bl[c][e] = (short)(wws[e] & 0xffffu);
      }
    }
#pragma unroll
    for (int it = 0; it < 4; it++){
      uint2 aw = *(const uint2*)(Ab + (size_t)(it * 16 + m) * 2048 + j0 + q * 8);
      int b[8];
#pragma unroll
      for (int e = 0; e < 4; e++){ b[e] = (aw.x >> (8*e)) & 255; b[e+4] = (aw.y >> (8*e)) & 255; }
#pragma unroll
      for (int c = 0; c < 5; c++){
        short8v am;
#pragma unroll
        for (int e = 0; e < 8; e++) am[e] = (short)((b[e] == c) ? 0x3F80 : 0);
        acc[it] = __builtin_amdgcn_mfma_f32_16x16x32_bf16(am, bh[c], acc[it], 0, 0, 0);
        acc[it] = __builtin_amdgcn_mfma_f32_16x16x32_bf16(am, bl[c], acc[it], 0, 0, 0);
      }
    }
  }
  float* op = aggp + (size_t)kc * 262144;
#pragma unroll
  for (int it = 0; it < 4; it++){
#pragma unroll
    for (int reg = 0; reg < 4; reg++)
      op[(size_t)(r0 + it * 16 + q * 4 + reg) * 64 + h0 + m] = acc[it][reg];
  }
}

// ---------------------------------------------------------------------------
// K4: hidden. Reduces 16 aggp partials; u-side denom counted inline from LT row
// (reference du-quirk), v-side = di. Then z=relu(inv*agg+b), sigmoid dense.
// ---------------------------------------------------------------------------
__global__ __launch_bounds__(256) void k_hidden(const float* __restrict__ aggp, const u8* __restrict__ LT,
    const int* __restrict__ di,
    const float* __restrict__ gc_b, const float* __restrict__ dense_w, const float* __restrict__ dense_b,
    float* __restrict__ hidden){
  int wid = threadIdx.x >> 6, lane = threadIdx.x & 63;
  int r = blockIdx.x * 4 + wid;
  float a = 0.f;
#pragma unroll
  for (int kc = 0; kc < 16; kc++) a += aggp[(size_t)kc * 262144 + (size_t)r * 64 + lane];
  int cnt;
  if (r < 2048){
    const uint4* rp = (const uint4*)(LT + (size_t)r * 2048);
    uint4 w1 = rp[lane * 2], w2 = rp[lane * 2 + 1];
    int c2 = cnt_not5(w1.x) + cnt_not5(w1.y) + cnt_not5(w1.z) + cnt_not5(w1.w)
           + cnt_not5(w2.x) + cnt_not5(w2.y) + cnt_not5(w2.z) + cnt_not5(w2.w);
#pragma unroll
    for (int o = 32; o > 0; o >>= 1) c2 += __shfl_down(c2, o);
    cnt = __shfl(c2, 0);
  } else {
    cnt = di[r - 2048];
  }
  float inv = (cnt > 0) ? (1.0f / (float)cnt) : 0.0f;
  float bsum = 0.f;
#pragma unroll
  for (int c = 0; c < 5; c++) bsum += gc_b[c * 64 + lane];
  float z = fmaxf(a * inv + bsum, 0.f);
  __shared__ float zb[4][64];
  zb[wid][lane] = z;
  __syncthreads();
  if (lane < 32){
    float s = dense_b[lane];
#pragma unroll
    for (int h = 0; h < 64; h++) s += zb[wid][h] * dense_w[h * 32 + lane];
    hidden[(size_t)r * 32 + lane] = 1.0f / (1.0f + __expf(-s));
  }
}

// ---------------------------------------------------------------------------
// K5: MFMA logits (r7/r12 form).
// ---------------------------------------------------------------------------
#define EPI(l, lab, outp) do{ \
  float mx = fmaxf(fmaxf(fmaxf(l[0], l[1]), fmaxf(l[2], l[3])), l[4]); \
  float e0 = __expf(l[0]-mx), e1 = __expf(l[1]-mx), e2 = __expf(l[2]-mx), e3 = __expf(l[3]-mx), e4 = __expf(l[4]-mx); \
  float ssum = e0 + e1 + e2 + e3 + e4; \
  *(outp) = (e1 + 2.f*e2 + 3.f*e3 + 4.f*e4) / ssum; \
  if ((lab) < 5){ \
    int pred = 0; float bm = l[0]; \
    if (l[1] > bm){ bm = l[1]; pred = 1; } \
    if (l[2] > bm){ bm = l[2]; pred = 2; } \
    if (l[3] > bm){ bm = l[3]; pred = 3; } \
    if (l[4] > bm){ bm = l[4]; pred = 4; } \
    float ll = (lab)==0 ? l[0] : ((lab)==1 ? l[1] : ((lab)==2 ? l[2] : ((lab)==3 ? l[3] : l[4]))); \
    lsum += __logf(ssum) + mx - ll; \
    acnt += (pred == (lab)); \
  } \
}while(0)

__global__ __launch_bounds__(256) void k_logits(const float* __restrict__ hidden, const float* __restrict__ dec_w,
    const u8* __restrict__ L, float* __restrict__ mhat, float* __restrict__ lpart, int* __restrict__ apart){
  __shared__ float hu_s[512];          // 16 x 32
  __shared__ float tsf[5 * 16 * 36];   // padded stride 36
  int tid = threadIdx.x;
  int lane = tid & 63, w = tid >> 6;
  int i0 = blockIdx.y * 16;
  if (tid < 128) ((float4*)hu_s)[tid] = ((const float4*)(hidden + (size_t)i0 * 32))[tid];
  __syncthreads();
  for (int idx = tid; idx < 2560; idx += 256){
    int c = idx >> 9; int rem = idx & 511; int ii = rem >> 5; int e = rem & 31;
    const float* wc = dec_w + (size_t)c * 1024 + e;
    const float* hr = hu_s + ii * 32;
    float s = 0.f;
#pragma unroll
    for (int d = 0; d < 32; d++) s += hr[d] * wc[d * 32];
    tsf[(c * 16 + ii) * 36 + e] = s;
  }
  __syncthreads();
  int m = lane & 15, q = lane >> 4;
  short8v a_hi[5], a_lo[5];
#pragma unroll
  for (int c = 0; c < 5; c++){
    const float* p = &tsf[(c * 16 + m) * 36 + q * 8];
    float fa[8];
    *(float4*)&fa[0] = *(const float4*)p;
    *(float4*)&fa[4] = *(const float4*)(p + 4);
    split8(fa, a_hi[c], a_lo[c]);
  }
  const float* hv = hidden + 2048 * 32;
  float lsum = 0.f; int acnt = 0;
  int jw0 = blockIdx.x * 256 + w * 64;
#pragma unroll
  for (int jj = 0; jj < 4; jj++){
    int j0 = jw0 + jj * 16;
    const float* pb = hv + (size_t)(j0 + m) * 32 + q * 8;
    float fb[8];
    *(float4*)&fb[0] = *(const float4*)pb;
    *(float4*)&fb[4] = *(const float4*)(pb + 4);
    short8v b_hi, b_lo;
    split8(fb, b_hi, b_lo);
    f32x4 acc[5];
    f32x4 z4 = {0.f, 0.f, 0.f, 0.f};
#pragma unroll
    for (int c = 0; c < 5; c++){
      f32x4 a = __builtin_amdgcn_mfma_f32_16x16x32_bf16(a_hi[c], b_hi, z4, 0, 0, 0);
      a = __builtin_amdgcn_mfma_f32_16x16x32_bf16(a_hi[c], b_lo, a, 0, 0, 0);
      a = __builtin_amdgcn_mfma_f32_16x16x32_bf16(a_lo[c], b_hi, a, 0, 0, 0);
      acc[c] = a;
    }
    int jcol = j0 + m;
#pragma unroll
    for (int r = 0; r < 4; r++){
      int irow = i0 + q * 4 + r;
      float l5[5] = {acc[0][r], acc[1][r], acc[2][r], acc[3][r], acc[4][r]};
      int lab = L[(size_t)irow * 2048 + jcol];
      EPI(l5, lab, mhat + (size_t)irow * 2048 + jcol);
    }
  }
#pragma unroll
  for (int o = 32; o > 0; o >>= 1){ lsum += __shfl_down(lsum, o); acnt += __shfl_down(acnt, o); }
  __shared__ float wl[4]; __shared__ int wa[4];
  if (lane == 0){ wl[w] = lsum; wa[w] = acnt; }
  __syncthreads();
  if (tid == 0){
    int pb = blockIdx.y * 8 + blockIdx.x;
    lpart[pb] = wl[0] + wl[1] + wl[2] + wl[3];
    apart[pb] = wa[0] + wa[1] + wa[2] + wa[3];
  }
}

// ---------------------------------------------------------------------------
// K6: final reduce over 1024 partials + n_obs = sum(di)
// ---------------------------------------------------------------------------
__global__ __launch_bounds__(256) void k_final(const float* __restrict__ lpart, const int* __restrict__ apart,
                                               const int* __restrict__ di, float* __restrict__ out){
  __shared__ float lred[256];
  __shared__ int ared[256], nred[256];
  int tid = threadIdx.x;
  float ls = 0.f; int as = 0;
#pragma unroll
  for (int k = 0; k < 4; k++){ ls += lpart[tid + k * 256]; as += apart[tid + k * 256]; }
  int ns = 0;
#pragma unroll
  for (int k = 0; k < 8; k++) ns += di[tid + k * 256];
  lred[tid] = ls; ared[tid] = as; nred[tid] = ns;
  __syncthreads();
  for (int s = 128; s > 0; s >>= 1){
    if (tid < s){ lred[tid] += lred[tid + s]; ared[tid] += ared[tid + s]; nred[tid] += nred[tid + s]; }
    __syncthreads();
  }
  if (tid == 0){
    float n = fmaxf((float)nred[0], 1.0f);
    out[0] = lred[0] / n;
    out[1] = ((float)ared[0]) / n;
  }
}

extern "C" void kernel_launch(void* const* d_in, const int* in_sizes, int n_in,
                              void* d_out, int out_size, void* d_ws, size_t ws_size,
                              hipStream_t stream){
  const int*   u       = (const int*)d_in[0];
  const int*   v       = (const int*)d_in[1];
  const float* ratings = (const float*)d_in[2];
  const float* u_emb   = (const float*)d_in[3];
  const float* v_emb   = (const float*)d_in[4];
  const float* gc_w    = (const float*)d_in[5];
  const float* gc_b    = (const float*)d_in[6];
  const float* dense_w = (const float*)d_in[7];
  const float* dense_b = (const float*)d_in[8];
  const float* dec_w   = (const float*)d_in[9];
  float* out = (float*)d_out;
  char* ws = (char*)d_ws;

  u8*    L       = (u8*)(ws + 0);                 // 4 MB
  u8*    LT      = (u8*)(ws + 4194304);           // 4 MB
  u32*   SP      = (u32*)(ws + 8388608);          // 5 MB: [5][64][4096] packed bf16 hi|lo
  float* aggp    = (float*)(ws + 13631488);       // 16 MB: [16][4096][64] k-chunk partials
  float* hidden  = (float*)(ws + 30408704);       // 512 KB: [4096][32]
  int*   di      = (int*)(ws + 30932992);         // 8 KB
  float* lpart   = (float*)(ws + 30941184);       // 4 KB: [1024]
  int*   apart   = (int*)(ws + 30945280);         // 4 KB: [1024]

  k_labels <<<2048, 256, 0, stream>>>(u, v, ratings, L, di);
  k_trsup  <<<1344, 256, 0, stream>>>(L, LT, u, v, u_emb, v_emb, gc_w, SP);
  k_agg    <<<dim3(16, 64), 256, 0, stream>>>(L, LT, SP, aggp);
  k_hidden <<<1024, 256, 0, stream>>>(aggp, LT, di, gc_b, dense_w, dense_b, hidden);
  k_logits <<<dim3(8, 128), 256, 0, stream>>>(hidden, dec_w, L, out, lpart, apart);
  k_final  <<<1, 256, 0, stream>>>(lpart, apart, di, out + 4194304);
}

// Round 14
// 94.573 us; speedup vs baseline: 1.1036x; 1.1036x over previous
//
#include <hip/hip_runtime.h>
#include <hip/hip_bf16.h>
#include <cstdint>

#define RST 16777216  // 4096*4096 floats per rating class
typedef unsigned short u16;
typedef unsigned char u8;
typedef unsigned int u32;
typedef unsigned long long u64;
typedef __attribute__((ext_vector_type(8))) short short8v;   // 8 bf16 in 4 VGPRs
typedef __attribute__((ext_vector_type(4))) float f32x4;

__device__ __forceinline__ u16 f2bf(float x){
  unsigned int b = __float_as_uint(x);
  unsigned int r = (b + 0x7FFFu + ((b >> 16) & 1u)) >> 16;
  return (u16)r;
}
__device__ __forceinline__ float bf2f(u16 h){
  return __uint_as_float(((unsigned int)h) << 16);
}
__device__ __forceinline__ void split8(const float* fa, short8v& hi, short8v& lo){
#pragma unroll
  for (int e = 0; e < 8; e++){
    u16 h = f2bf(fa[e]);
    hi[e] = (short)h;
    lo[e] = (short)f2bf(fa[e] - bf2f(h));
  }
}
__device__ __forceinline__ int cnt_not5(u32 w){
  int c = 0;
  c += ((w & 255u) != 5u); c += (((w >> 8) & 255u) != 5u);
  c += (((w >> 16) & 255u) != 5u); c += ((w >> 24) != 5u);
  return c;
}

// ---------------------------------------------------------------------------
// K1: label extraction + di row-counts. One block per batch-row i. (r3 form)
// ---------------------------------------------------------------------------
__global__ __launch_bounds__(256) void k_labels(const int* __restrict__ u, const int* __restrict__ v,
                                                const float* __restrict__ ratings, u8* __restrict__ L,
                                                int* __restrict__ di){
  __shared__ float row[4096];
  __shared__ int wsum[4];
  int i = blockIdx.x;
  int tid = threadIdx.x;
  int lane = tid & 63, wid = tid >> 6;
  int U = u[i];
  int j0 = tid * 8;
  int vj[8];
#pragma unroll
  for (int k = 0; k < 8; k++) vj[k] = v[j0 + k];
  int lab[8];
#pragma unroll
  for (int k = 0; k < 8; k++) lab[k] = 5;
  const float* rbase = ratings + (size_t)U * 4096;
  for (int c = 0; c < 5; c++){
    const float4* src = (const float4*)(rbase + (size_t)c * RST);
#pragma unroll
    for (int k = 0; k < 4; k++) ((float4*)row)[tid + k*256] = src[tid + k*256];
    __syncthreads();
#pragma unroll
    for (int k = 0; k < 8; k++) if (row[vj[k]] > 0.5f) lab[k] = c;
    __syncthreads();
  }
  unsigned int lo = 0, hi = 0;
  int cnt = 0;
#pragma unroll
  for (int k = 0; k < 4; k++){
    lo |= ((unsigned)lab[k]) << (8*k); hi |= ((unsigned)lab[k+4]) << (8*k);
    cnt += (lab[k] != 5); cnt += (lab[k+4] != 5);
  }
  *(uint2*)(L + (size_t)i * 2048 + j0) = make_uint2(lo, hi);
#pragma unroll
  for (int o = 32; o > 0; o >>= 1) cnt += __shfl_down(cnt, o);
  if (lane == 0) wsum[wid] = cnt;
  __syncthreads();
  if (tid == 0) di[i] = wsum[0] + wsum[1] + wsum[2] + wsum[3];
}

// ---------------------------------------------------------------------------
// K2: fused [byte transpose L->LT] + [support via split-bf16 MFMA].
// Support output stored in MFMA-B FRAGMENT ORDER:
//   SPF[((c*128 + jc)*4 + ht)*512 + lane*8 + e]  (u32 = bf16hi<<16 | bf16lo)
//   holds S(c, n = jc*32 + (lane>>4)*8 + e, h = ht*16 + (lane&15)).
// Epilogue routes acc through a 16KB LDS pack buffer -> one contiguous
// coalesced 16KB store per block.
// ---------------------------------------------------------------------------
__global__ __launch_bounds__(256) void k_trsup(const u8* __restrict__ L, u8* __restrict__ LT,
    const int* __restrict__ u, const int* __restrict__ v,
    const float* __restrict__ u_emb, const float* __restrict__ v_emb, const float* __restrict__ gc_w,
    u32* __restrict__ SPF){
  __shared__ union { u8 tile[64][64]; u32 pack[4096]; } sm;
  int tid = threadIdx.x;
  if (blockIdx.x < 1024){
    int jb = blockIdx.x & 31, ib = blockIdx.x >> 5;
    int i0 = ib * 64, j0 = jb * 64;
    int r = tid >> 2, cq = tid & 3;
    uint4 d = *(const uint4*)(L + (size_t)(i0 + r) * 2048 + j0 + cq * 16);
    *(uint4*)&sm.tile[r][cq * 16] = d;
    __syncthreads();
    u8 ob[16];
#pragma unroll
    for (int k = 0; k < 16; k++) ob[k] = sm.tile[cq * 16 + k][r];
    *(uint4*)(LT + (size_t)(j0 + r) * 2048 + i0 + cq * 16) = *(uint4*)ob;
  } else {
    int b = blockIdx.x - 1024;
    int c = b >> 6, nblk = b & 63;
    int lane = tid & 63, wv = tid >> 6;
    int m = lane & 15, q = lane >> 4;
    int n0 = nblk * 64;
    bool uside = (n0 < 2048);
    const int* nidx = uside ? u : v;
    const float* emb = uside ? u_emb : v_emb;
    int nbase = uside ? n0 : (n0 - 2048);
    int h0 = wv * 16;
    short8v bh[2], bl[2];
#pragma unroll
    for (int ch = 0; ch < 2; ch++){
      const float* wp = gc_w + c * 4096 + (ch * 32 + q * 8) * 64 + h0 + m;
      float fb[8];
#pragma unroll
      for (int e = 0; e < 8; e++) fb[e] = wp[e * 64];
      split8(fb, bh[ch], bl[ch]);
    }
#pragma unroll
    for (int rt = 0; rt < 4; rt++){
      const float* xr = emb + (size_t)nidx[nbase + rt * 16 + m] * 64;
      f32x4 acc = {0.f, 0.f, 0.f, 0.f};
#pragma unroll
      for (int ch = 0; ch < 2; ch++){
        float fa[8];
        *(float4*)&fa[0] = *(const float4*)(xr + ch * 32 + q * 8);
        *(float4*)&fa[4] = *(const float4*)(xr + ch * 32 + q * 8 + 4);
        short8v ah, al;
        split8(fa, ah, al);
        acc = __builtin_amdgcn_mfma_f32_16x16x32_bf16(ah, bh[ch], acc, 0, 0, 0);
        acc = __builtin_amdgcn_mfma_f32_16x16x32_bf16(ah, bl[ch], acc, 0, 0, 0);
        acc = __builtin_amdgcn_mfma_f32_16x16x32_bf16(al, bh[ch], acc, 0, 0, 0);
      }
#pragma unroll
      for (int reg = 0; reg < 4; reg++){
        float val = acc[reg];
        u16 vh = f2bf(val);
        u16 vl = f2bf(val - bf2f(vh));
        int n = n0 + rt * 16 + q * 4 + reg;       // absolute n (0..4095)
        int jc_l = (n >> 5) & 1;                  // 2 jc blocks per 64-n block
        int kk = n & 31;
        int lanep = m + ((kk >> 3) << 4);
        int ep = kk & 7;
        sm.pack[((jc_l * 4 + wv) * 64 + lanep) * 8 + ep] = (((u32)vh) << 16) | (u32)vl;
      }
    }
    __syncthreads();
    // coalesced 16KB store: SPF region for (c, jc0..jc0+1, all ht) is contiguous
    int jc0 = n0 >> 5;
    u32* dst = SPF + ((size_t)(c * 128 + jc0) * 4) * 512;
#pragma unroll
    for (int p = 0; p < 4; p++){
      int t = p * 1024 + tid * 4;
      *(uint4*)&dst[t] = *(const uint4*)&sm.pack[t];
    }
  }
}

// ---------------------------------------------------------------------------
// K3: DENSE masked-MFMA aggregate, coalesced. Grid (8 k-chunks x 64 row-blocks).
// A-tile (64 rows x 256B labels) staged in LDS (coalesced, padded rows);
// B-frags from SPF = one contiguous 2KB read per wave per (c,ks).
// 2 MFMAs per class (mask exact). Partials to aggp[kc][r][h].
// ---------------------------------------------------------------------------
__global__ __launch_bounds__(256) void k_agg(const u8* __restrict__ L, const u8* __restrict__ LT,
    const u32* __restrict__ SPF, float* __restrict__ aggp){
  __shared__ u8 As[64][272];    // 256B cols + 16B pad
  int tid = threadIdx.x;
  int lane = tid & 63, wv = tid >> 6;
  int m = lane & 15, q = lane >> 4;
  int kc = blockIdx.x;        // 0..7
  int rb = blockIdx.y;        // 0..63
  int r0 = rb * 64;
  bool uside = (r0 < 2048);
  const u8* Ab = uside ? (L + (size_t)r0 * 2048) : (LT + (size_t)(r0 - 2048) * 2048);
  int jcb = (uside ? 64 : 0) + kc * 8;   // base jc into SPF (opposite-side S)
  // stage A: 64 rows x 256 bytes, coalesced
#pragma unroll
  for (int p = 0; p < 4; p++){
    int idx = p * 256 + tid;
    int row = idx >> 4, ci = idx & 15;
    *(uint4*)&As[row][ci * 16] = *(const uint4*)(Ab + (size_t)row * 2048 + kc * 256 + ci * 16);
  }
  __syncthreads();
  f32x4 acc[4];
#pragma unroll
  for (int it = 0; it < 4; it++) acc[it] = (f32x4){0.f, 0.f, 0.f, 0.f};
  for (int ks = 0; ks < 8; ks++){
    short8v bh[5], bl[5];
#pragma unroll
    for (int c = 0; c < 5; c++){
      const uint4* bp = (const uint4*)(SPF + ((size_t)((c * 128 + jcb + ks) * 4 + wv) * 64 + lane) * 8);
      uint4 wA = bp[0], wB = bp[1];
      u32 wws[8] = {wA.x, wA.y, wA.z, wA.w, wB.x, wB.y, wB.z, wB.w};
#pragma unroll
      for (int e = 0; e < 8; e++){
        bh[c][e] = (short)(wws[e] >> 16);
        bl[c][e] = (short)(wws[e] & 0xffffu);
      }
    }
#pragma unroll
    for (int it = 0; it < 4; it++){
      u64 a8 = *(const u64*)&As[it * 16 + m][ks * 32 + q * 8];
      int b[8];
#pragma unroll
      for (int e = 0; e < 8; e++) b[e] = (int)((a8 >> (8 * e)) & 255u);
#pragma unroll
      for (int c = 0; c < 5; c++){
        short8v am;
#pragma unroll
        for (int e = 0; e < 8; e++) am[e] = (short)((b[e] == c) ? 0x3F80 : 0);
        acc[it] = __builtin_amdgcn_mfma_f32_16x16x32_bf16(am, bh[c], acc[it], 0, 0, 0);
        acc[it] = __builtin_amdgcn_mfma_f32_16x16x32_bf16(am, bl[c], acc[it], 0, 0, 0);
      }
    }
  }
  float* op = aggp + (size_t)kc * 262144;
  int h0 = wv * 16;
#pragma unroll
  for (int it = 0; it < 4; it++){
#pragma unroll
    for (int reg = 0; reg < 4; reg++)
      op[(size_t)(r0 + it * 16 + q * 4 + reg) * 64 + h0 + m] = acc[it][reg];
  }
}

// ---------------------------------------------------------------------------
// K4: hidden. Reduces 8 aggp partials; u-side denom counted inline from LT row
// (reference du-quirk), v-side = di. Then z=relu(inv*agg+b), sigmoid dense.
// ---------------------------------------------------------------------------
__global__ __launch_bounds__(256) void k_hidden(const float* __restrict__ aggp, const u8* __restrict__ LT,
    const int* __restrict__ di,
    const float* __restrict__ gc_b, const float* __restrict__ dense_w, const float* __restrict__ dense_b,
    float* __restrict__ hidden){
  int wid = threadIdx.x >> 6, lane = threadIdx.x & 63;
  int r = blockIdx.x * 4 + wid;
  float a = 0.f;
#pragma unroll
  for (int kc = 0; kc < 8; kc++) a += aggp[(size_t)kc * 262144 + (size_t)r * 64 + lane];
  int cnt;
  if (r < 2048){
    const uint4* rp = (const uint4*)(LT + (size_t)r * 2048);
    uint4 w1 = rp[lane * 2], w2 = rp[lane * 2 + 1];
    int c2 = cnt_not5(w1.x) + cnt_not5(w1.y) + cnt_not5(w1.z) + cnt_not5(w1.w)
           + cnt_not5(w2.x) + cnt_not5(w2.y) + cnt_not5(w2.z) + cnt_not5(w2.w);
#pragma unroll
    for (int o = 32; o > 0; o >>= 1) c2 += __shfl_down(c2, o);
    cnt = __shfl(c2, 0);
  } else {
    cnt = di[r - 2048];
  }
  float inv = (cnt > 0) ? (1.0f / (float)cnt) : 0.0f;
  float bsum = 0.f;
#pragma unroll
  for (int c = 0; c < 5; c++) bsum += gc_b[c * 64 + lane];
  float z = fmaxf(a * inv + bsum, 0.f);
  __shared__ float zb[4][64];
  zb[wid][lane] = z;
  __syncthreads();
  if (lane < 32){
    float s = dense_b[lane];
#pragma unroll
    for (int h = 0; h < 64; h++) s += zb[wid][h] * dense_w[h * 32 + lane];
    hidden[(size_t)r * 32 + lane] = 1.0f / (1.0f + __expf(-s));
  }
}

// ---------------------------------------------------------------------------
// K5: MFMA logits (r7/r12 form).
// ---------------------------------------------------------------------------
#define EPI(l, lab, outp) do{ \
  float mx = fmaxf(fmaxf(fmaxf(l[0], l[1]), fmaxf(l[2], l[3])), l[4]); \
  float e0 = __expf(l[0]-mx), e1 = __expf(l[1]-mx), e2 = __expf(l[2]-mx), e3 = __expf(l[3]-mx), e4 = __expf(l[4]-mx); \
  float ssum = e0 + e1 + e2 + e3 + e4; \
  *(outp) = (e1 + 2.f*e2 + 3.f*e3 + 4.f*e4) / ssum; \
  if ((lab) < 5){ \
    int pred = 0; float bm = l[0]; \
    if (l[1] > bm){ bm = l[1]; pred = 1; } \
    if (l[2] > bm){ bm = l[2]; pred = 2; } \
    if (l[3] > bm){ bm = l[3]; pred = 3; } \
    if (l[4] > bm){ bm = l[4]; pred = 4; } \
    float ll = (lab)==0 ? l[0] : ((lab)==1 ? l[1] : ((lab)==2 ? l[2] : ((lab)==3 ? l[3] : l[4]))); \
    lsum += __logf(ssum) + mx - ll; \
    acnt += (pred == (lab)); \
  } \
}while(0)

__global__ __launch_bounds__(256) void k_logits(const float* __restrict__ hidden, const float* __restrict__ dec_w,
    const u8* __restrict__ L, float* __restrict__ mhat, float* __restrict__ lpart, int* __restrict__ apart){
  __shared__ float hu_s[512];          // 16 x 32
  __shared__ float tsf[5 * 16 * 36];   // padded stride 36
  int tid = threadIdx.x;
  int lane = tid & 63, w = tid >> 6;
  int i0 = blockIdx.y * 16;
  if (tid < 128) ((float4*)hu_s)[tid] = ((const float4*)(hidden + (size_t)i0 * 32))[tid];
  __syncthreads();
  for (int idx = tid; idx < 2560; idx += 256){
    int c = idx >> 9; int rem = idx & 511; int ii = rem >> 5; int e = rem & 31;
    const float* wc = dec_w + (size_t)c * 1024 + e;
    const float* hr = hu_s + ii * 32;
    float s = 0.f;
#pragma unroll
    for (int d = 0; d < 32; d++) s += hr[d] * wc[d * 32];
    tsf[(c * 16 + ii) * 36 + e] = s;
  }
  __syncthreads();
  int m = lane & 15, q = lane >> 4;
  short8v a_hi[5], a_lo[5];
#pragma unroll
  for (int c = 0; c < 5; c++){
    const float* p = &tsf[(c * 16 + m) * 36 + q * 8];
    float fa[8];
    *(float4*)&fa[0] = *(const float4*)p;
    *(float4*)&fa[4] = *(const float4*)(p + 4);
    split8(fa, a_hi[c], a_lo[c]);
  }
  const float* hv = hidden + 2048 * 32;
  float lsum = 0.f; int acnt = 0;
  int jw0 = blockIdx.x * 256 + w * 64;
#pragma unroll
  for (int jj = 0; jj < 4; jj++){
    int j0 = jw0 + jj * 16;
    const float* pb = hv + (size_t)(j0 + m) * 32 + q * 8;
    float fb[8];
    *(float4*)&fb[0] = *(const float4*)pb;
    *(float4*)&fb[4] = *(const float4*)(pb + 4);
    short8v b_hi, b_lo;
    split8(fb, b_hi, b_lo);
    f32x4 acc[5];
    f32x4 z4 = {0.f, 0.f, 0.f, 0.f};
#pragma unroll
    for (int c = 0; c < 5; c++){
      f32x4 a = __builtin_amdgcn_mfma_f32_16x16x32_bf16(a_hi[c], b_hi, z4, 0, 0, 0);
      a = __builtin_amdgcn_mfma_f32_16x16x32_bf16(a_hi[c], b_lo, a, 0, 0, 0);
      a = __builtin_amdgcn_mfma_f32_16x16x32_bf16(a_lo[c], b_hi, a, 0, 0, 0);
      acc[c] = a;
    }
    int jcol = j0 + m;
#pragma unroll
    for (int r = 0; r < 4; r++){
      int irow = i0 + q * 4 + r;
      float l5[5] = {acc[0][r], acc[1][r], acc[2][r], acc[3][r], acc[4][r]};
      int lab = L[(size_t)irow * 2048 + jcol];
      EPI(l5, lab, mhat + (size_t)irow * 2048 + jcol);
    }
  }
#pragma unroll
  for (int o = 32; o > 0; o >>= 1){ lsum += __shfl_down(lsum, o); acnt += __shfl_down(acnt, o); }
  __shared__ float wl[4]; __shared__ int wa[4];
  if (lane == 0){ wl[w] = lsum; wa[w] = acnt; }
  __syncthreads();
  if (tid == 0){
    int pb = blockIdx.y * 8 + blockIdx.x;
    lpart[pb] = wl[0] + wl[1] + wl[2] + wl[3];
    apart[pb] = wa[0] + wa[1] + wa[2] + wa[3];
  }
}

// ---------------------------------------------------------------------------
// K6: final reduce over 1024 partials + n_obs = sum(di)
// ---------------------------------------------------------------------------
__global__ __launch_bounds__(256) void k_final(const float* __restrict__ lpart, const int* __restrict__ apart,
                                               const int* __restrict__ di, float* __restrict__ out){
  __shared__ float lred[256];
  __shared__ int ared[256], nred[256];
  int tid = threadIdx.x;
  float ls = 0.f; int as = 0;
#pragma unroll
  for (int k = 0; k < 4; k++){ ls += lpart[tid + k * 256]; as += apart[tid + k * 256]; }
  int ns = 0;
#pragma unroll
  for (int k = 0; k < 8; k++) ns += di[tid + k * 256];
  lred[tid] = ls; ared[tid] = as; nred[tid] = ns;
  __syncthreads();
  for (int s = 128; s > 0; s >>= 1){
    if (tid < s){ lred[tid] += lred[tid + s]; ared[tid] += ared[tid + s]; nred[tid] += nred[tid + s]; }
    __syncthreads();
  }
  if (tid == 0){
    float n = fmaxf((float)nred[0], 1.0f);
    out[0] = lred[0] / n;
    out[1] = ((float)ared[0]) / n;
  }
}

extern "C" void kernel_launch(void* const* d_in, const int* in_sizes, int n_in,
                              void* d_out, int out_size, void* d_ws, size_t ws_size,
                              hipStream_t stream){
  const int*   u       = (const int*)d_in[0];
  const int*   v       = (const int*)d_in[1];
  const float* ratings = (const float*)d_in[2];
  const float* u_emb   = (const float*)d_in[3];
  const float* v_emb   = (const float*)d_in[4];
  const float* gc_w    = (const float*)d_in[5];
  const float* gc_b    = (const float*)d_in[6];
  const float* dense_w = (const float*)d_in[7];
  const float* dense_b = (const float*)d_in[8];
  const float* dec_w   = (const float*)d_in[9];
  float* out = (float*)d_out;
  char* ws = (char*)d_ws;

  u8*    L       = (u8*)(ws + 0);                 // 4 MB
  u8*    LT      = (u8*)(ws + 4194304);           // 4 MB
  u32*   SPF     = (u32*)(ws + 8388608);          // 5 MB: fragment-order packed support
  float* aggp    = (float*)(ws + 13631488);       // 8 MB: [8][4096][64] k-chunk partials
  float* hidden  = (float*)(ws + 22020096);       // 512 KB: [4096][32]
  int*   di      = (int*)(ws + 22544384);         // 8 KB
  float* lpart   = (float*)(ws + 22552576);       // 4 KB: [1024]
  int*   apart   = (int*)(ws + 22556672);         // 4 KB: [1024]

  k_labels <<<2048, 256, 0, stream>>>(u, v, ratings, L, di);
  k_trsup  <<<1344, 256, 0, stream>>>(L, LT, u, v, u_emb, v_emb, gc_w, SPF);
  k_agg    <<<dim3(8, 64), 256, 0, stream>>>(L, LT, SPF, aggp);
  k_hidden <<<1024, 256, 0, stream>>>(aggp, LT, di, gc_b, dense_w, dense_b, hidden);
  k_logits <<<dim3(8, 128), 256, 0, stream>>>(hidden, dec_w, L, out, lpart, apart);
  k_final  <<<1, 256, 0, stream>>>(lpart, apart, di, out + 4194304);
}